// Round 9
// baseline (31.301 us; speedup 1.0000x reference)
//
#include <hip/hip_runtime.h>

#define Hd    256
#define OUTD  10
#define DDEP  10
#define KSTR  12
#define TLEN  8192
#define NTHR  1024
#define NBLK  256
#define TILE  2048

// Module-scope sync state: zero-init at load, monotonic across all replays.
// g_flag counts completed K-publications; g_ticket counts consumer-block
// arrivals (255 per replay) -> gen = ticket / 255, target flag = gen+1.
__device__ unsigned g_ticket, g_flag;

__device__ __forceinline__ int ph(int j) { return j + (j >> 5); }

// LDS floats: yb[22528] (transpose buf; block0 reuses first 5120 as W3s+Vs),
// Ks[120+pad] @22528, xs @22656 (2058 logical, swizzled).
#define OFF_KS  22528
#define OFF_XS  22656
#define XS_LOG  (TILE + DDEP)
#define SMEM_FLOATS (OFF_XS + XS_LOG + (XS_LOG >> 5) + 8)

__global__ __launch_bounds__(NTHR, 4) void fused_rnn_kernel(
    const float* __restrict__ x, const float* __restrict__ w1g,
    const float* __restrict__ W2, const float* __restrict__ W3,
    float* __restrict__ y, float* __restrict__ Kb)
{
    __shared__ float smem[SMEM_FLOATS];
    __shared__ unsigned sgen;
    float* yb = smem;
    float* Ks = smem + OFF_KS;
    float* xs = smem + OFF_XS;

    const int tid = threadIdx.x;
    const int bid = blockIdx.x;
    const int b   = bid >> 2;
    const int t0  = (bid & 3) * TILE;
    const float* xb = x + b * TLEN;

    if (bid == 0) {
        // ---------------- K builder (producer) ----------------
        float* W3s = yb;                 // [10*256]
        float* Vs  = yb + 2560;          // [DDEP][256] history
        const int r = tid >> 2, q = tid & 3;   // row r, col quarter q
        const float4* W2v = (const float4*)W2;
        float4 A[16];                    // W2 row-chunk, bank-phase rotated
        #pragma unroll
        for (int k = 0; k < 16; ++k)
            A[k] = W2v[r * 64 + q * 16 + ((k + 4 * q) & 15)];

        for (int i = tid; i < OUTD * Hd; i += NTHR) W3s[i] = W3[i];
        if (tid < Hd) Vs[tid] = w1g[tid];
        for (int j = tid; j < XS_LOG; j += NTHR) {      // own conv tile
            const int g = t0 - DDEP + j;
            xs[ph(j)] = (g >= 0) ? xb[g] : 0.0f;
        }
        __syncthreads();

        // chain: v_{d+1} = W2 * v_d  (9 serial LDS roundtrips)
        #pragma unroll 1
        for (int d = 0; d < DDEP - 1; ++d) {
            const float4* vsrc = (const float4*)(Vs + d * Hd);
            float4 a = make_float4(0.f, 0.f, 0.f, 0.f);
            #pragma unroll
            for (int k = 0; k < 16; ++k) {
                const float4 vv = vsrc[q * 16 + ((k + 4 * q) & 15)];
                a.x = fmaf(A[k].x, vv.x, a.x);
                a.y = fmaf(A[k].y, vv.y, a.y);
                a.z = fmaf(A[k].z, vv.z, a.z);
                a.w = fmaf(A[k].w, vv.w, a.w);
            }
            float p = (a.x + a.y) + (a.z + a.w);
            p += __shfl_xor(p, 1);
            p += __shfl_xor(p, 2);
            if (q == 0) Vs[(d + 1) * Hd + r] = p;
            __syncthreads();
        }

        // K[d][o] = W3[o] . v_d : wave w handles d = w (w < 10)
        {
            const int w = tid >> 6, l = tid & 63;
            if (w < DDEP) {
                const float4 vv = ((const float4*)(Vs + w * Hd))[l];
                #pragma unroll
                for (int o = 0; o < OUTD; ++o) {
                    const float4 wv = ((const float4*)(W3s + o * Hd))[l];
                    float p = fmaf(wv.x, vv.x,
                              fmaf(wv.y, vv.y,
                              fmaf(wv.z, vv.z, wv.w * vv.w)));
                    p += __shfl_xor(p, 1);  p += __shfl_xor(p, 2);
                    p += __shfl_xor(p, 4);  p += __shfl_xor(p, 8);
                    p += __shfl_xor(p, 16); p += __shfl_xor(p, 32);
                    if (l == 0) Ks[w * KSTR + o] = p;
                }
                if (l == 1) { Ks[w * KSTR + 10] = 0.f; Ks[w * KSTR + 11] = 0.f; }
            }
        }
        __syncthreads();
        if (tid < DDEP * KSTR) Kb[tid] = Ks[tid];
        __syncthreads();
        if (tid == 0) {
            __threadfence();             // release: K visible at coherent point
            __hip_atomic_fetch_add(&g_flag, 1u, __ATOMIC_RELEASE,
                                   __HIP_MEMORY_SCOPE_AGENT);
        }
        // falls through to conv; Ks already live in LDS
    } else {
        // ---------------- consumers: stage x, then wait for K ----------------
        if (tid == 0)
            sgen = __hip_atomic_fetch_add(&g_ticket, 1u, __ATOMIC_RELAXED,
                                          __HIP_MEMORY_SCOPE_AGENT) / (NBLK - 1);
        for (int j = tid; j < XS_LOG; j += NTHR) {
            const int g = t0 - DDEP + j;
            xs[ph(j)] = (g >= 0) ? xb[g] : 0.0f;
        }
        __syncthreads();
        if (tid == 0) {
            const unsigned target = sgen + 1u;
            unsigned guard = 0;
            // RELAXED polling (r4-proven: no per-poll cache maintenance)
            while (__hip_atomic_load(&g_flag, __ATOMIC_RELAXED,
                                     __HIP_MEMORY_SCOPE_AGENT) < target) {
                __builtin_amdgcn_s_sleep(8);
                if (++guard > 4000000u) break;      // fail loud, not hang
            }
            (void)__hip_atomic_load(&g_flag, __ATOMIC_ACQUIRE,
                                    __HIP_MEMORY_SCOPE_AGENT);
        }
        __syncthreads();
        if (tid < DDEP * KSTR) Ks[tid] = Kb[tid];
        __syncthreads();
    }

    // ---------------- causal FIR, 2 positions per thread ----------------
    const int ub = tid * 2;
    float acc0[OUTD], acc1[OUTD];
    #pragma unroll
    for (int o = 0; o < OUTD; ++o) { acc0[o] = 0.f; acc1[o] = 0.f; }

    float wn0 = xs[ph(ub + DDEP)];
    float wn1 = xs[ph(ub + DDEP + 1)];

    #pragma unroll
    for (int d = 0; d < DDEP; ++d) {
        const float4 kA = *(const float4*)&Ks[d * KSTR];
        const float4 kB = *(const float4*)&Ks[d * KSTR + 4];
        const float2 kC = *(const float2*)&Ks[d * KSTR + 8];
        acc0[0] = fmaf(kA.x, wn0, acc0[0]);  acc1[0] = fmaf(kA.x, wn1, acc1[0]);
        acc0[1] = fmaf(kA.y, wn0, acc0[1]);  acc1[1] = fmaf(kA.y, wn1, acc1[1]);
        acc0[2] = fmaf(kA.z, wn0, acc0[2]);  acc1[2] = fmaf(kA.z, wn1, acc1[2]);
        acc0[3] = fmaf(kA.w, wn0, acc0[3]);  acc1[3] = fmaf(kA.w, wn1, acc1[3]);
        acc0[4] = fmaf(kB.x, wn0, acc0[4]);  acc1[4] = fmaf(kB.x, wn1, acc1[4]);
        acc0[5] = fmaf(kB.y, wn0, acc0[5]);  acc1[5] = fmaf(kB.y, wn1, acc1[5]);
        acc0[6] = fmaf(kB.z, wn0, acc0[6]);  acc1[6] = fmaf(kB.z, wn1, acc1[6]);
        acc0[7] = fmaf(kB.w, wn0, acc0[7]);  acc1[7] = fmaf(kB.w, wn1, acc1[7]);
        acc0[8] = fmaf(kC.x, wn0, acc0[8]);  acc1[8] = fmaf(kC.x, wn1, acc1[8]);
        acc0[9] = fmaf(kC.y, wn0, acc0[9]);  acc1[9] = fmaf(kC.y, wn1, acc1[9]);
        wn1 = wn0;
        wn0 = xs[ph(ub + DDEP - 1 - d)];
    }

    // transpose via LDS (stride 11), then fully-coalesced float4 stores
    #pragma unroll
    for (int o = 0; o < OUTD; ++o) {
        yb[ub * 11 + o]      = acc0[o];
        yb[ub * 11 + 11 + o] = acc1[o];
    }
    __syncthreads();

    float* yg = y + ((size_t)b * TLEN + t0) * OUTD;
    #pragma unroll
    for (int r5 = 0; r5 < 5; ++r5) {
        const int l = (r5 * NTHR + tid) * 4;
        float4 v;
        v.x = yb[l     + (l    ) / 10];
        v.y = yb[l + 1 + (l + 1) / 10];
        v.z = yb[l + 2 + (l + 2) / 10];
        v.w = yb[l + 3 + (l + 3) / 10];
        *(float4*)(yg + l) = v;
    }
}

extern "C" void kernel_launch(void* const* d_in, const int* in_sizes, int n_in,
                              void* d_out, int out_size, void* d_ws, size_t ws_size,
                              hipStream_t stream)
{
    const float* x  = (const float*)d_in[0];   // (64, 8192)
    const float* w1 = (const float*)d_in[1];   // (256, 1) contiguous
    const float* W2 = (const float*)d_in[2];   // (256, 256)
    const float* W3 = (const float*)d_in[3];   // (10, 256)
    float* y  = (float*)d_out;
    float* Kb = (float*)d_ws;                  // 120 floats

    fused_rnn_kernel<<<NBLK, dim3(NTHR), 0, stream>>>(x, w1, W2, W3, y, Kb);
}